// Round 5
// baseline (69.374 us; speedup 1.0000x reference)
//
#include <hip/hip_runtime.h>

// NT-Xent loss, B=4096, D=256, N=8192, T=0.5
// loss = [ sum_r ( log(sum_{c!=r} exp(2*f_r.f_c)) - 2*f_r.f_pos(r) ) ] / N^2
// v5: MX-fp8 32x32x64 (unit scales). Stage the WHOLE 128-col B panel (32KB)
// into LDS once -> ONE barrier per kernel, zero barriers in the main loop.
// 8 waves x 32 rows, conflict-free 16B-lane-stride LDS layout.

#define B_ROWS 4096
#define DIM 256
#define NTOT 8192
#define NCHUNK 64        // col chunks of 128
#define CHUNK_COLS 128
#define BLK_ROWS 256

#define SCALE_IN 1.69864360f   // sqrt(2*log2(e)): acc = 2*log2e*dot, exp2(acc)=exp(2 dot)

typedef int i32x4 __attribute__((ext_vector_type(4)));
typedef int i32x8 __attribute__((ext_vector_type(8)));
typedef float f32x16 __attribute__((ext_vector_type(16)));
typedef __attribute__((address_space(1))) const unsigned int gas_uint;
typedef __attribute__((address_space(3))) unsigned int las_uint;

__device__ __forceinline__ float wave_reduce_add(float v) {
#pragma unroll
    for (int m = 1; m < 64; m <<= 1) v += __shfl_xor(v, m, 64);
    return v;
}

__device__ __forceinline__ i32x8 ld32g(const unsigned char* p) {
    const i32x4 lo = *reinterpret_cast<const i32x4*>(p);
    const i32x4 hi = *reinterpret_cast<const i32x4*>(p + 16);
    return __builtin_shufflevector(lo, hi, 0, 1, 2, 3, 4, 5, 6, 7);
}

// K1: 4 waves/block, one row-pair per wave. Normalize (fp32), write fp8 feats
// scaled by SCALE_IN, exact fp32 positive-pair sims.
__global__ __launch_bounds__(256) void k_norm(const float* __restrict__ zi,
                                              const float* __restrict__ zj,
                                              unsigned char* __restrict__ F8,
                                              float* __restrict__ pos_sim) {
    const int wave = threadIdx.x >> 6;
    const int lane = threadIdx.x & 63;
    const int r = blockIdx.x * 4 + wave;
    const float4 vi = reinterpret_cast<const float4*>(zi + (size_t)r * DIM)[lane];
    const float4 vj = reinterpret_cast<const float4*>(zj + (size_t)r * DIM)[lane];
    float si = vi.x * vi.x + vi.y * vi.y + vi.z * vi.z + vi.w * vi.w;
    float sj = vj.x * vj.x + vj.y * vj.y + vj.z * vj.z + vj.w * vj.w;
    si = wave_reduce_add(si);
    sj = wave_reduce_add(sj);
    const float ri = SCALE_IN / sqrtf(si);
    const float rj = SCALE_IN / sqrtf(sj);
    const float a0 = vi.x * ri, a1 = vi.y * ri, a2 = vi.z * ri, a3 = vi.w * ri;
    const float b0 = vj.x * rj, b1 = vj.y * rj, b2 = vj.z * rj, b3 = vj.w * rj;
    const float inv2 = 1.0f / (SCALE_IN * SCALE_IN);
    float dot = (a0 * b0 + a1 * b1 + a2 * b2 + a3 * b3) * inv2;
    dot = wave_reduce_add(dot);
    int pa = __builtin_amdgcn_cvt_pk_fp8_f32(a0, a1, 0, false);
    pa = __builtin_amdgcn_cvt_pk_fp8_f32(a2, a3, pa, true);
    int pb = __builtin_amdgcn_cvt_pk_fp8_f32(b0, b1, 0, false);
    pb = __builtin_amdgcn_cvt_pk_fp8_f32(b2, b3, pb, true);
    reinterpret_cast<int*>(F8 + (size_t)r * DIM)[lane] = pa;
    reinterpret_cast<int*>(F8 + (size_t)(r + B_ROWS) * DIM)[lane] = pb;
    if (lane == 0) {
        const float ps = 2.0f * dot;
        pos_sim[r] = ps;
        pos_sim[r + B_ROWS] = ps;
    }
}

// K2: MX-fp8 sim GEMM + fused exp2 row-sum, barrier-free main loop.
// Block: 8 waves x 32 rows x 128 cols. B panel 128x256B = 32KB staged once.
// LDS chunk q=((c64*4+ks)*2+h)*64+lane at byte q*16: col=c64*32+(lane&31),
// k=ks*64+(lane>>5)*32+h*16. ds_read_b128 lanes stride 16B = conflict-free.
__global__ __launch_bounds__(512, 4) void k_simsum(const unsigned char* __restrict__ F8,
                                                   float* __restrict__ Spart) {
    __shared__ unsigned char Bsm[32768];
    const int bid0 = blockIdx.x;
    const int bid = (bid0 & 7) * 256 + (bid0 >> 3);   // XCD: 8 col-chunks per XCD
    const int ch = bid >> 5;
    const int rt = bid & 31;
    const int tid = threadIdx.x;
    const int wave = tid >> 6;
    const int lane = tid & 63;
    const int c32 = lane & 31;
    const int l5 = lane >> 5;

    const int wrow0 = rt * BLK_ROWS + wave * 32;
    const int col0 = ch * CHUNK_COLS;

    // stage entire panel: 2048 16B chunks / 512 thr = 4 each
#pragma unroll
    for (int i = 0; i < 4; ++i) {
        const int q = i * 512 + tid;
        const int c64 = q >> 9;
        const int ks = (q >> 7) & 3;
        const int h = (q >> 6) & 1;
        const int l = q & 63;
        const unsigned char* src = F8 + (size_t)(col0 + c64 * 32 + (l & 31)) * DIM
                                   + ks * 64 + (l >> 5) * 32 + h * 16;
        __builtin_amdgcn_global_load_lds((gas_uint*)src,
                                         (las_uint*)(&Bsm[(i * 512 + wave * 64) * 16]),
                                         16, 0, 0);
    }

    // A fragments: 4 ks x 32 contiguous k-bytes per lane (row = wrow0 + c32)
    i32x8 a[4];
    {
        const unsigned char* ap = F8 + (size_t)(wrow0 + c32) * DIM + l5 * 32;
#pragma unroll
        for (int ks = 0; ks < 4; ++ks) a[ks] = ld32g(ap + ks * 64);
    }

    asm volatile("s_waitcnt vmcnt(0)");
    __syncthreads();
    // ---- no synchronization below this line ----

    float sums[16];
#pragma unroll
    for (int g = 0; g < 16; ++g) sums[g] = 0.0f;

#pragma unroll
    for (int c64 = 0; c64 < 4; ++c64) {
        f32x16 acc = {};
#pragma unroll
        for (int ks = 0; ks < 4; ++ks) {
            const unsigned char* base = &Bsm[(c64 * 4 + ks) * 2048 + lane * 16];
            const i32x8 b = __builtin_shufflevector(
                *reinterpret_cast<const i32x4*>(base),
                *reinterpret_cast<const i32x4*>(base + 1024), 0, 1, 2, 3, 4, 5, 6, 7);
            acc = __builtin_amdgcn_mfma_scale_f32_32x32x64_f8f6f4(
                a[ks], b, acc, 0, 0, 0, 0x7F7F7F7F, 0, 0x7F7F7F7F);
        }

        const int cb = col0 + c64 * 32;
        if (wrow0 == cb) {
#pragma unroll
            for (int g = 0; g < 16; ++g) {
                const int rowid = (g & 3) + 8 * (g >> 2) + 4 * l5;
                const float e = exp2f(acc[g]);
                sums[g] += (rowid == c32) ? 0.0f : e;
            }
        } else {
#pragma unroll
            for (int g = 0; g < 16; ++g) sums[g] += exp2f(acc[g]);
        }
    }

    // reduce each row's partial across the 32 lanes holding its columns
#pragma unroll
    for (int g = 0; g < 16; ++g) {
        float s = sums[g];
        s += __shfl_xor(s, 1, 64);
        s += __shfl_xor(s, 2, 64);
        s += __shfl_xor(s, 4, 64);
        s += __shfl_xor(s, 8, 64);
        s += __shfl_xor(s, 16, 64);
        if (c32 == 0) {
            const int row = wrow0 + (g & 3) + 8 * (g >> 2) + 4 * l5;
            Spart[(size_t)ch * NTOT + row] = s;
        }
    }
}

// K3a: 32 blocks x 256 thr, one row each: S = sum chunks, local = log(S)-pos.
__global__ __launch_bounds__(256) void k_reduce(const float* __restrict__ Spart,
                                                const float* __restrict__ pos_sim,
                                                float* __restrict__ Bpart) {
    __shared__ float red[4];
    const int r = blockIdx.x * 256 + threadIdx.x;
    float s = 0.0f;
#pragma unroll
    for (int c = 0; c < NCHUNK; ++c) s += Spart[(size_t)c * NTOT + r];
    float local = logf(s) - pos_sim[r];
    local = wave_reduce_add(local);
    if ((threadIdx.x & 63) == 0) red[threadIdx.x >> 6] = local;
    __syncthreads();
    if (threadIdx.x == 0) Bpart[blockIdx.x] = red[0] + red[1] + red[2] + red[3];
}

// K3b: single wave folds 32 block partials.
__global__ void k_fin(const float* __restrict__ Bpart, float* __restrict__ out) {
    float v = (threadIdx.x < 32) ? Bpart[threadIdx.x] : 0.0f;
    v = wave_reduce_add(v);
    if (threadIdx.x == 0) out[0] = v / ((float)NTOT * (float)NTOT);
}

extern "C" void kernel_launch(void* const* d_in, const int* in_sizes, int n_in,
                              void* d_out, int out_size, void* d_ws, size_t ws_size,
                              hipStream_t stream) {
    (void)in_sizes; (void)n_in; (void)out_size; (void)ws_size;
    const float* zi = (const float*)d_in[0];
    const float* zj = (const float*)d_in[1];
    float* out = (float*)d_out;

    char* ws = (char*)d_ws;
    unsigned char* F8 = (unsigned char*)ws;                     // 2 MiB fp8 feats (pre-scaled)
    float* pos_sim = (float*)(ws + 2097152);                    // 32 KiB
    float* Spart = (float*)(ws + 2097152 + 65536);              // 2 MiB (64 chunks)
    float* Bpart = (float*)(ws + 2097152 + 65536 + 2097152);    // 128 B

    k_norm<<<B_ROWS / 4, 256, 0, stream>>>(zi, zj, F8, pos_sim);
    k_simsum<<<2048, 512, 0, stream>>>(F8, Spart);
    k_reduce<<<32, 256, 0, stream>>>(Spart, pos_sim, Bpart);
    k_fin<<<1, 64, 0, stream>>>(Bpart, out);
}

// Round 6
// 42.566 us; speedup vs baseline: 1.6298x; 1.6298x over previous
//
#include <hip/hip_runtime.h>

// NT-Xent loss, B=4096, D=256, N=8192, T=0.5
// loss = [ sum_r ( log(sum_{c!=r} exp(2*f_r.f_c)) - 2*f_r.f_pos(r) ) ] / N^2
// v6: v4 skeleton (MX-fp8 32x32x64, conflict-free 16B-stride LDS, dbuf) with
// CHUNK_COLS=512 -> grid 512 = exactly 2 blocks/CU; halves A-refetch and
// per-block fixed costs (A loads, shuffle tail, launch).

#define B_ROWS 4096
#define DIM 256
#define NTOT 8192
#define NCHUNK 16        // col chunks of 512
#define CHUNK_COLS 512
#define TILE_COLS 64
#define NTILE 8
#define BLK_ROWS 256

#define SCALE_IN 1.69864360f   // sqrt(2*log2(e)): acc = 2*log2e*dot, exp2(acc)=exp(2 dot)

typedef int i32x4 __attribute__((ext_vector_type(4)));
typedef int i32x8 __attribute__((ext_vector_type(8)));
typedef float f32x16 __attribute__((ext_vector_type(16)));
typedef __attribute__((address_space(1))) const unsigned int gas_uint;
typedef __attribute__((address_space(3))) unsigned int las_uint;

__device__ __forceinline__ float wave_reduce_add(float v) {
#pragma unroll
    for (int m = 1; m < 64; m <<= 1) v += __shfl_xor(v, m, 64);
    return v;
}

__device__ __forceinline__ i32x8 ld32g(const unsigned char* p) {
    const i32x4 lo = *reinterpret_cast<const i32x4*>(p);
    const i32x4 hi = *reinterpret_cast<const i32x4*>(p + 16);
    return __builtin_shufflevector(lo, hi, 0, 1, 2, 3, 4, 5, 6, 7);
}

// K1: 4 waves/block, one row-pair per wave. Normalize (fp32), write fp8 feats
// scaled by SCALE_IN, exact fp32 positive-pair sims.
__global__ __launch_bounds__(256) void k_norm(const float* __restrict__ zi,
                                              const float* __restrict__ zj,
                                              unsigned char* __restrict__ F8,
                                              float* __restrict__ pos_sim) {
    const int wave = threadIdx.x >> 6;
    const int lane = threadIdx.x & 63;
    const int r = blockIdx.x * 4 + wave;
    const float4 vi = reinterpret_cast<const float4*>(zi + (size_t)r * DIM)[lane];
    const float4 vj = reinterpret_cast<const float4*>(zj + (size_t)r * DIM)[lane];
    float si = vi.x * vi.x + vi.y * vi.y + vi.z * vi.z + vi.w * vi.w;
    float sj = vj.x * vj.x + vj.y * vj.y + vj.z * vj.z + vj.w * vj.w;
    si = wave_reduce_add(si);
    sj = wave_reduce_add(sj);
    const float ri = SCALE_IN / sqrtf(si);
    const float rj = SCALE_IN / sqrtf(sj);
    const float a0 = vi.x * ri, a1 = vi.y * ri, a2 = vi.z * ri, a3 = vi.w * ri;
    const float b0 = vj.x * rj, b1 = vj.y * rj, b2 = vj.z * rj, b3 = vj.w * rj;
    const float inv2 = 1.0f / (SCALE_IN * SCALE_IN);
    float dot = (a0 * b0 + a1 * b1 + a2 * b2 + a3 * b3) * inv2;
    dot = wave_reduce_add(dot);
    int pa = __builtin_amdgcn_cvt_pk_fp8_f32(a0, a1, 0, false);
    pa = __builtin_amdgcn_cvt_pk_fp8_f32(a2, a3, pa, true);
    int pb = __builtin_amdgcn_cvt_pk_fp8_f32(b0, b1, 0, false);
    pb = __builtin_amdgcn_cvt_pk_fp8_f32(b2, b3, pb, true);
    reinterpret_cast<int*>(F8 + (size_t)r * DIM)[lane] = pa;
    reinterpret_cast<int*>(F8 + (size_t)(r + B_ROWS) * DIM)[lane] = pb;
    if (lane == 0) {
        const float ps = 2.0f * dot;
        pos_sim[r] = ps;
        pos_sim[r + B_ROWS] = ps;
    }
}

// K2: MX-fp8 sim GEMM (32x32x64, unit scales) + fused exp2 row-sum.
// 8 waves x 32 rows x 512 cols. B tile = 64 cols x 256B = 16KB, double-
// buffered. LDS: chunk q = ks*256 + cblk*128 + h*64 + lane at byte q*16;
// ds_read_b128 lanes stride 16B = conflict-free; gload_lds dest wave-linear.
__global__ __launch_bounds__(512, 4) void k_simsum(const unsigned char* __restrict__ F8,
                                                   float* __restrict__ Spart) {
    __shared__ unsigned char Bsm[2][16384];
    const int bid0 = blockIdx.x;
    const int bid = (bid0 & 7) * 64 + (bid0 >> 3);   // XCD: 2 col-chunks per XCD
    const int ch = bid >> 5;
    const int rt = bid & 31;
    const int tid = threadIdx.x;
    const int wave = tid >> 6;
    const int lane = tid & 63;
    const int c32 = lane & 31;
    const int l5 = lane >> 5;

    const int wrow0 = rt * BLK_ROWS + wave * 32;
    const int col0 = ch * CHUNK_COLS;

    // A fragments first (overlap with staging): 4 ks x 32 contiguous k-bytes
    i32x8 a[4];
    {
        const unsigned char* ap = F8 + (size_t)(wrow0 + c32) * DIM + l5 * 32;
#pragma unroll
        for (int ks = 0; ks < 4; ++ks) a[ks] = ld32g(ap + ks * 64);
    }

    // stage tile t (64 cols x K=256) into buf. 1024 16B chunks / 512 thr.
    auto stage = [&](int buf, int t) {
        const int colbase = col0 + t * TILE_COLS;
#pragma unroll
        for (int i = 0; i < 2; ++i) {
            const int q = i * 512 + tid;
            const int ks = q >> 8;
            const int rem = q & 255;
            const int cblk = rem >> 7;
            const int h = (rem >> 6) & 1;
            const int l = rem & 63;
            const unsigned char* src = F8 + (size_t)(colbase + cblk * 32 + (l & 31)) * DIM
                                       + ks * 64 + (l >> 5) * 32 + h * 16;
            __builtin_amdgcn_global_load_lds((gas_uint*)src,
                                             (las_uint*)(&Bsm[buf][(i * 512 + wave * 64) * 16]),
                                             16, 0, 0);
        }
    };

    stage(0, 0);

    float sums[16];
#pragma unroll
    for (int g = 0; g < 16; ++g) sums[g] = 0.0f;

    asm volatile("s_waitcnt vmcnt(0)");
    __syncthreads();

    for (int t = 0; t < NTILE; ++t) {
        const int buf = t & 1;
        if (t + 1 < NTILE) stage(buf ^ 1, t + 1);

        f32x16 acc0 = {};
        f32x16 acc1 = {};
#pragma unroll
        for (int ks = 0; ks < 4; ++ks) {
            const unsigned char* base = &Bsm[buf][ks * 4096 + lane * 16];
            const i32x8 b0 = __builtin_shufflevector(
                *reinterpret_cast<const i32x4*>(base),
                *reinterpret_cast<const i32x4*>(base + 1024), 0, 1, 2, 3, 4, 5, 6, 7);
            const i32x8 b1 = __builtin_shufflevector(
                *reinterpret_cast<const i32x4*>(base + 2048),
                *reinterpret_cast<const i32x4*>(base + 3072), 0, 1, 2, 3, 4, 5, 6, 7);
            acc0 = __builtin_amdgcn_mfma_scale_f32_32x32x64_f8f6f4(
                a[ks], b0, acc0, 0, 0, 0, 0x7F7F7F7F, 0, 0x7F7F7F7F);
            acc1 = __builtin_amdgcn_mfma_scale_f32_32x32x64_f8f6f4(
                a[ks], b1, acc1, 0, 0, 0, 0x7F7F7F7F, 0, 0x7F7F7F7F);
        }

        const int cb = col0 + t * TILE_COLS;
        const bool d0 = (wrow0 == cb);
        const bool d1 = (wrow0 == cb + 32);
        if (d0 | d1) {
#pragma unroll
            for (int g = 0; g < 16; ++g) {
                const int rowid = (g & 3) + 8 * (g >> 2) + 4 * l5;
                float e0 = exp2f(acc0[g]);
                float e1 = exp2f(acc1[g]);
                if (d0 && rowid == c32) e0 = 0.0f;
                if (d1 && rowid == c32) e1 = 0.0f;
                sums[g] += e0 + e1;
            }
        } else {
#pragma unroll
            for (int g = 0; g < 16; ++g)
                sums[g] += exp2f(acc0[g]) + exp2f(acc1[g]);
        }

        asm volatile("s_waitcnt vmcnt(0)");
        __syncthreads();
    }

    // reduce each row's partial across the 32 lanes holding its columns
#pragma unroll
    for (int g = 0; g < 16; ++g) {
        float s = sums[g];
        s += __shfl_xor(s, 1, 64);
        s += __shfl_xor(s, 2, 64);
        s += __shfl_xor(s, 4, 64);
        s += __shfl_xor(s, 8, 64);
        s += __shfl_xor(s, 16, 64);
        if (c32 == 0) {
            const int row = wrow0 + (g & 3) + 8 * (g >> 2) + 4 * l5;
            Spart[(size_t)ch * NTOT + row] = s;
        }
    }
}

// K3a: 32 blocks x 256 thr, one row each: S = sum chunks, local = log(S)-pos.
__global__ __launch_bounds__(256) void k_reduce(const float* __restrict__ Spart,
                                                const float* __restrict__ pos_sim,
                                                float* __restrict__ Bpart) {
    __shared__ float red[4];
    const int r = blockIdx.x * 256 + threadIdx.x;
    float s = 0.0f;
#pragma unroll
    for (int c = 0; c < NCHUNK; ++c) s += Spart[(size_t)c * NTOT + r];
    float local = logf(s) - pos_sim[r];
    local = wave_reduce_add(local);
    if ((threadIdx.x & 63) == 0) red[threadIdx.x >> 6] = local;
    __syncthreads();
    if (threadIdx.x == 0) Bpart[blockIdx.x] = red[0] + red[1] + red[2] + red[3];
}

// K3b: single wave folds 32 block partials.
__global__ void k_fin(const float* __restrict__ Bpart, float* __restrict__ out) {
    float v = (threadIdx.x < 32) ? Bpart[threadIdx.x] : 0.0f;
    v = wave_reduce_add(v);
    if (threadIdx.x == 0) out[0] = v / ((float)NTOT * (float)NTOT);
}

extern "C" void kernel_launch(void* const* d_in, const int* in_sizes, int n_in,
                              void* d_out, int out_size, void* d_ws, size_t ws_size,
                              hipStream_t stream) {
    (void)in_sizes; (void)n_in; (void)out_size; (void)ws_size;
    const float* zi = (const float*)d_in[0];
    const float* zj = (const float*)d_in[1];
    float* out = (float*)d_out;

    char* ws = (char*)d_ws;
    unsigned char* F8 = (unsigned char*)ws;                     // 2 MiB fp8 feats (pre-scaled)
    float* pos_sim = (float*)(ws + 2097152);                    // 32 KiB
    float* Spart = (float*)(ws + 2097152 + 65536);              // 512 KiB (16 chunks)
    float* Bpart = (float*)(ws + 2097152 + 65536 + 524288);     // 128 B

    k_norm<<<B_ROWS / 4, 256, 0, stream>>>(zi, zj, F8, pos_sim);
    k_simsum<<<512, 512, 0, stream>>>(F8, Spart);
    k_reduce<<<32, 256, 0, stream>>>(Spart, pos_sim, Bpart);
    k_fin<<<1, 64, 0, stream>>>(Bpart, out);
}